// Round 16
// baseline (350.299 us; speedup 1.0000x reference)
//
#include <hip/hip_runtime.h>
#include <stdint.h>

#define NN 20000
#define NE 320000

typedef unsigned short us16;
typedef __attribute__((ext_vector_type(8))) short short8;
typedef __attribute__((ext_vector_type(4))) float f32x4;

union U4 { uint4 v; us16 s[8]; unsigned u[4]; };
union U2 { uint2 v; us16 s[4]; };

__device__ __forceinline__ float b2f(us16 u){ return __uint_as_float(((unsigned)u)<<16); }
__device__ __forceinline__ us16 f2b(float f){
  unsigned u = __float_as_uint(f);
  u += 0x7fffu + ((u>>16)&1u);
  return (us16)(u>>16);
}

__device__ __forceinline__ void gll16(const void* g, void* l){
  __builtin_amdgcn_global_load_lds((const __attribute__((address_space(1))) void*)g,
                                   (__attribute__((address_space(3))) void*)l, 16, 0, 0);
}

// ---------------- merged misc: gat_w cvt + conv2 wprep + conv1 wprep + wl/wr + hist ----------------
__global__ __launch_bounds__(256) void k_misc(
    const float* __restrict__ gatw, us16* __restrict__ Wb,
    const float* __restrict__ w1, const float* __restrict__ w2, const float* __restrict__ w3,
    us16* __restrict__ Wt,
    const float* __restrict__ c1w1, const float* __restrict__ c1w2, const float* __restrict__ c1w3,
    const float* __restrict__ rp_w, us16* __restrict__ Wt1,
    const float* __restrict__ attnl, const float* __restrict__ attnr,
    float* __restrict__ wl, float* __restrict__ wr,
    const int* __restrict__ dst, int* __restrict__ counts)
{
  const int b = blockIdx.x, tid = threadIdx.x;
  if(b < 256){
    int i = b*256 + tid;
    float4 v = *(const float4*)(gatw + (size_t)i*4);
    U2 o;
    o.s[0]=f2b(v.x); o.s[1]=f2b(v.y); o.s[2]=f2b(v.z); o.s[3]=f2b(v.w);
    *(uint2*)(Wb + (size_t)i*4) = o.v;
  } else if(b < 400){
    int i = (b-256)*256 + tid;       // 36864: Wt[s][co3(96)][ci(128)]
    int s = i/12288, rem = i%12288;
    int co3 = rem>>7, ci = rem&127;
    const float* w = (co3<32) ? w1 : (co3<64) ? w2 : w3;
    Wt[i] = f2b(w[(co3&31)*384 + ci*3 + s]);
  } else if(b < 448){
    int i = (b-400)*256 + tid;       // 12288: Wt1[s][co3(128)][ci(32)]
    int s = i>>12, rem = i&4095;
    int co3 = rem>>5, ci = rem&31;
    float v;
    if(co3 < 96){
      const float* w = (co3<32) ? c1w1 : (co3<64) ? c1w2 : c1w3;
      v = w[(co3&31)*96 + ci*3 + s];
    } else {
      v = (s==1) ? rp_w[(co3-96)*32 + ci] : 0.f;
    }
    Wt1[i] = f2b(v);
  } else if(b < 480){
    int bb = b-448;                   // 0..31
    int sel = bb>>4, hd = (bb>>2)&3, fq = bb&3;
    const float* attn = sel ? attnr : attnl;
    int k = tid;
    float s = 0.f;
    int f0 = fq*64;
    #pragma unroll 8
    for(int f=f0; f<f0+64; f++)
      s = fmaf(attn[hd*256+f], gatw[(size_t)(hd*256+f)*256 + k], s);
    atomicAdd(&((sel ? wr : wl)[hd*256+k]), s);
  } else {
    int e = (b-480)*256 + tid;
    if(e < NE) atomicAdd(&counts[dst[e]], 1);
  }
}

// ---------------- conv1 (+residual k1) as MFMA GEMM + coalesced CSR scan tail block ----------------
__global__ __launch_bounds__(256) void k_gemm1(
    const float* __restrict__ X, const us16* __restrict__ Wt1,
    const float* __restrict__ b1, const float* __restrict__ b2, const float* __restrict__ b3,
    const float* __restrict__ rp_b,
    us16* __restrict__ gc1, us16* __restrict__ resid,
    float* __restrict__ bn0_sum, float* __restrict__ bn0_sq,
    const int* __restrict__ counts, int* __restrict__ offsets, int* __restrict__ cursor)
{
  __shared__ float smemF[5760];            // 23040 B: As 12800 B + Bs(one tap) 10240 B
  __shared__ float redS[32], redQ[32];
  __shared__ int wred[4];
  const int tid = threadIdx.x;
  if(blockIdx.x < 1250){
    us16* As = (us16*)smemF;                // [16][10][40] = 6400 us16
    us16* Bs = As + 6400;                   // [128][40]    = 5120 us16 (one tap)
    if(tid<32){ redS[tid]=0.f; redQ[tid]=0.f; }
    const int node0 = blockIdx.x*16;
    const int lane = tid&63, wv = tid>>6;
    const int mrow = lane&15, kg = (lane>>4)*8;
    for(int idx=tid; idx<1024; idx+=256){
      int n = idx>>6, rem = idx&63, slot = (rem>>5)*9, ci = rem&31;
      As[n*400 + slot*40 + ci] = 0;
    }
    #pragma unroll
    for(int i=0;i<4;i++){
      int idx = i*256 + tid;
      int n = idx>>6, rem = idx&63, ci = rem>>1, tq = rem&1;
      float4 xv = *(const float4*)(X + (size_t)(node0+n)*256 + ci*8 + tq*4);
      us16* p = &As[n*400 + (tq*4+1)*40 + ci];
      p[0]   = f2b(xv.x);
      p[40]  = f2b(xv.y);
      p[80]  = f2b(xv.z);
      p[120] = f2b(xv.w);
    }
    f32x4 acc[2][8] = {};
    for(int s=0; s<3; s++){
      if(s) __syncthreads();               // WAR: prior tap's mfma reads done before overwrite
      #pragma unroll
      for(int i=0;i<2;i++){
        int c = i*256 + tid;               // 512 uint4 = 128 co x 4 chunks
        int co = c>>2, cq = c&3;
        *(uint4*)&Bs[co*40 + cq*8] = *(const uint4*)(Wt1 + s*4096 + co*32 + cq*8);
      }
      __syncthreads();                     // covers As staging too (s==0)
      short8 af[2], bfr[8];
      #pragma unroll
      for(int i=0;i<2;i++){
        int r = wv*32 + i*16 + mrow;
        af[i] = *(const short8*)&As[(r>>3)*400 + ((r&7)+s)*40 + kg];
      }
      #pragma unroll
      for(int j=0;j<8;j++)
        bfr[j] = *(const short8*)&Bs[(j*16 + mrow)*40 + kg];
      #pragma unroll
      for(int i=0;i<2;i++){
        #pragma unroll
        for(int j=0;j<8;j++)
          acc[i][j] = __builtin_amdgcn_mfma_f32_16x16x32_bf16(af[i], bfr[j], acc[i][j], 0, 0, 0);
      }
    }
    __syncthreads();                        // As/Bs dead; overlay output staging
    us16* Og = (us16*)smemF;                // [16 nodes][32 co][8 t] us16 = 8192 B
    us16* Or = Og + 4096;                   // 8192 B
    const int coA = lane&15, coB = coA+16;
    const float b1A=b1[coA], b2A=b2[coA], b3A=b3[coA], brA=rp_b[coA];
    const float b1B=b1[coB], b2B=b2[coB], b3B=b3[coB], brB=rp_b[coB];
    float sA=0.f, qA=0.f, sB=0.f, qB=0.f;
    const int g = lane>>4;
    #pragma unroll
    for(int i=0;i<2;i++){
      int node = wv*4 + i*2 + (g>>1);
      int t0 = (g&1)*4;
      U2 pA, pB, rA2, rB2;
      #pragma unroll
      for(int r=0;r<4;r++){
        float c1 = acc[i][0][r]+b1A, c2 = acc[i][2][r]+b2A, c3 = acc[i][4][r]+b3A;
        float rr = acc[i][6][r]+brA;
        float sg = 1.f/(1.f+__expf(-c2));
        float v = fmaf(c1,sg,c3); v = v>0.f ? v : 0.f;
        sA += v; qA += v*v;
        pA.s[r]=f2b(v); rA2.s[r]=f2b(rr);
        c1 = acc[i][1][r]+b1B; c2 = acc[i][3][r]+b2B; c3 = acc[i][5][r]+b3B;
        rr = acc[i][7][r]+brB;
        sg = 1.f/(1.f+__expf(-c2));
        v = fmaf(c1,sg,c3); v = v>0.f ? v : 0.f;
        sB += v; qB += v*v;
        pB.s[r]=f2b(v); rB2.s[r]=f2b(rr);
      }
      *(uint2*)&Og[node*256 + coA*8 + t0] = pA.v;
      *(uint2*)&Og[node*256 + coB*8 + t0] = pB.v;
      *(uint2*)&Or[node*256 + coA*8 + t0] = rA2.v;
      *(uint2*)&Or[node*256 + coB*8 + t0] = rB2.v;
    }
    sA += __shfl_xor(sA,16,64); sA += __shfl_xor(sA,32,64);
    qA += __shfl_xor(qA,16,64); qA += __shfl_xor(qA,32,64);
    sB += __shfl_xor(sB,16,64); sB += __shfl_xor(sB,32,64);
    qB += __shfl_xor(qB,16,64); qB += __shfl_xor(qB,32,64);
    if(lane < 16){
      atomicAdd(&redS[coA], sA); atomicAdd(&redQ[coA], qA);
      atomicAdd(&redS[coB], sB); atomicAdd(&redQ[coB], qB);
    }
    __syncthreads();
    #pragma unroll
    for(int i=0;i<2;i++){
      int idx = i*256 + tid;                // 512 uint4 each
      *(uint4*)(gc1   + (size_t)node0*256 + (size_t)idx*8) = *(const uint4*)&Og[idx*8];
      *(uint4*)(resid + (size_t)node0*256 + (size_t)idx*8) = *(const uint4*)&Or[idx*8];
    }
    if(tid<32)      atomicAdd(&bn0_sum[tid], redS[tid]);
    else if(tid<64) atomicAdd(&bn0_sq[tid-32], redQ[tid-32]);
  } else {
    // ---- CSR exclusive scan: tiled (1024/tile), wave shfl scan, coalesced int4 I/O ----
    const int lane = tid&63, wv = tid>>6;
    int running = 0;
    int4 cur;
    {
      int idx = tid*4;
      cur = *(const int4*)(counts + idx);
    }
    for(int t=0; t<20; t++){
      int4 nxt; nxt.x=0; nxt.y=0; nxt.z=0; nxt.w=0;
      if(t < 19){
        int idx = (t+1)*1024 + tid*4;
        if(idx+3 < NN) nxt = *(const int4*)(counts + idx);
        else {
          if(idx   < NN) nxt.x = counts[idx];
          if(idx+1 < NN) nxt.y = counts[idx+1];
          if(idx+2 < NN) nxt.z = counts[idx+2];
          if(idx+3 < NN) nxt.w = counts[idx+3];
        }
      }
      int s = cur.x + cur.y + cur.z + cur.w;
      int incl = s;
      #pragma unroll
      for(int off=1; off<64; off<<=1){
        int v = __shfl_up(incl, off, 64);
        if(lane >= off) incl += v;
      }
      if(lane==63) wred[wv] = incl;
      __syncthreads();
      int woff = 0, btot = 0;
      #pragma unroll
      for(int w2=0; w2<4; w2++){
        int x = wred[w2];
        btot += x;
        if(w2 < wv) woff += x;
      }
      int e0 = running + woff + incl - s;
      int idx = t*1024 + tid*4;
      int4 o; o.x=e0; o.y=e0+cur.x; o.z=o.y+cur.y; o.w=o.z+cur.z;
      if(idx+3 < NN){
        *(int4*)(offsets+idx) = o;
        *(int4*)(cursor+idx)  = o;
      } else {
        if(idx   < NN){ offsets[idx]  =o.x; cursor[idx]  =o.x; }
        if(idx+1 < NN){ offsets[idx+1]=o.y; cursor[idx+1]=o.y; }
        if(idx+2 < NN){ offsets[idx+2]=o.z; cursor[idx+2]=o.z; }
        if(idx+3 < NN){ offsets[idx+3]=o.w; cursor[idx+3]=o.w; }
      }
      running += btot;
      cur = nxt;
      __syncthreads();
    }
    if(tid==0) offsets[NN] = running;
  }
}

// ---------------- el/er from gc1 (bn0 folded): wave per node ----------------
__global__ __launch_bounds__(256) void k_eler2(const us16* __restrict__ gc1,
    const float* __restrict__ bn0_sum, const float* __restrict__ bn0_sq,
    const float* __restrict__ bn0g, const float* __restrict__ bn0b,
    const float* __restrict__ wl, const float* __restrict__ wr,
    float* __restrict__ el, float* __restrict__ er)
{
  __shared__ float sa[32], sb[32];
  const int tid = threadIdx.x;
  if(tid<32){
    float m = bn0_sum[tid]*(1.f/160000.f);
    float v = bn0_sq[tid]*(1.f/160000.f) - m*m;
    float a = bn0g[tid]*rsqrtf(v + 1e-5f);
    sa[tid] = a; sb[tid] = bn0b[tid] - m*a;
  }
  __syncthreads();
  const int wv = tid>>6, lane = tid&63;
  const int node = blockIdx.x*4 + wv;
  U2 g; g.v = *(const uint2*)(gc1 + (size_t)node*256 + lane*4);
  const float a = sa[lane>>1], b = sb[lane>>1];
  float xv[4];
  #pragma unroll
  for(int j=0;j<4;j++) xv[j] = fmaf(a, b2f(g.s[j]), b);
  float res[8];
  #pragma unroll
  for(int hd=0; hd<4; hd++){
    float4 lv = *(const float4*)(wl + hd*256 + lane*4);
    float4 rv = *(const float4*)(wr + hd*256 + lane*4);
    res[hd]   = xv[0]*lv.x + xv[1]*lv.y + xv[2]*lv.z + xv[3]*lv.w;
    res[4+hd] = xv[0]*rv.x + xv[1]*rv.y + xv[2]*rv.z + xv[3]*rv.w;
  }
  #pragma unroll
  for(int o=32;o;o>>=1){
    #pragma unroll
    for(int k=0;k<8;k++) res[k] += __shfl_xor(res[k], o, 64);
  }
  if(lane==0){
    #pragma unroll
    for(int hd=0;hd<4;hd++){ el[node*4+hd]=res[hd]; er[node*4+hd]=res[4+hd]; }
  }
}

// ---------------- scatter + edge scores ----------------
__global__ __launch_bounds__(256) void k_scatter(const int* __restrict__ src, const int* __restrict__ dst,
    int* __restrict__ cursor, int* __restrict__ esrc,
    const float* __restrict__ el, const float* __restrict__ er,
    float* __restrict__ ew)
{
  int e = blockIdx.x*256 + threadIdx.x;
  if(e < NE){
    int s = src[e], d = dst[e];
    int pos = atomicAdd(&cursor[d], 1);
    esrc[pos] = s;
    float4 lv = *(const float4*)(el + s*4);
    float4 rv = *(const float4*)(er + d*4);
    float4 sc;
    sc.x = lv.x+rv.x; sc.x = sc.x>0.f ? sc.x : 0.2f*sc.x;
    sc.y = lv.y+rv.y; sc.y = sc.y>0.f ? sc.y : 0.2f*sc.y;
    sc.z = lv.z+rv.z; sc.z = sc.z>0.f ? sc.z : 0.2f*sc.z;
    sc.w = lv.w+rv.w; sc.w = sc.w>0.f ? sc.w : 0.2f*sc.w;
    *(float4*)(ew + (size_t)pos*4) = sc;
  }
}

// ---------------- GAT aggregate in x-space: one wave per node, no LDS, no barriers ----------------
__global__ __launch_bounds__(256) void k_agg2(
    const int* __restrict__ offsets, const int* __restrict__ esrc,
    const float* __restrict__ ew, const us16* __restrict__ gc1,
    const float* __restrict__ bn0_sum, const float* __restrict__ bn0_sq,
    const float* __restrict__ bn0g, const float* __restrict__ bn0b,
    us16* __restrict__ Axg)
{
  const int tid = threadIdx.x;
  const int wv = tid>>6, lane = tid&63;
  const int node = blockIdx.x*4 + wv;
  const int ch = lane>>1;
  float mmn = bn0_sum[ch]*(1.f/160000.f);
  float vvn = bn0_sq[ch]*(1.f/160000.f) - mmn*mmn;
  float sa = bn0g[ch]*rsqrtf(vvn + 1e-5f);
  float sb = bn0b[ch] - mmn*sa;
  const int beg = offsets[node];
  const int deg = offsets[node+1] - beg;
  const int h = lane>>4, i0 = lane&15;
  float m = -3.0e38f;
  for(int i=i0; i<deg; i+=16) m = fmaxf(m, ew[(size_t)(beg+i)*4 + h]);
  m = fmaxf(m, __shfl_xor(m,1,64)); m = fmaxf(m, __shfl_xor(m,2,64));
  m = fmaxf(m, __shfl_xor(m,4,64)); m = fmaxf(m, __shfl_xor(m,8,64));
  float den = 0.f;
  for(int i=i0; i<deg; i+=16) den += __expf(ew[(size_t)(beg+i)*4 + h] - m);
  den += __shfl_xor(den,1,64); den += __shfl_xor(den,2,64);
  den += __shfl_xor(den,4,64); den += __shfl_xor(den,8,64);
  const float m0=__shfl(m,0,64),   m1=__shfl(m,16,64),  m2=__shfl(m,32,64),  m3=__shfl(m,48,64);
  const float d0=__shfl(den,0,64), d1=__shfl(den,16,64),d2=__shfl(den,32,64),d3=__shfl(den,48,64);
  const float v0=d0>0.f?1.f/d0:0.f, v1=d1>0.f?1.f/d1:0.f,
              v2=d2>0.f?1.f/d2:0.f, v3=d3>0.f?1.f/d3:0.f;
  float a0c[4]={},a1c[4]={},a2c[4]={},a3c[4]={};
  #pragma unroll 4
  for(int j=0; j<deg; j++){
    int pos = beg+j;
    float4 w4 = *(const float4*)(ew + (size_t)pos*4);
    int sN = esrc[pos];
    U2 hv; hv.v = *(const uint2*)(gc1 + (size_t)sN*256 + lane*4);
    float e0 = __expf(w4.x-m0)*v0;
    float e1 = __expf(w4.y-m1)*v1;
    float e2 = __expf(w4.z-m2)*v2;
    float e3 = __expf(w4.w-m3)*v3;
    #pragma unroll
    for(int kk=0;kk<4;kk++){
      float x = b2f(hv.s[kk]);
      a0c[kk] = fmaf(e0,x,a0c[kk]);
      a1c[kk] = fmaf(e1,x,a1c[kk]);
      a2c[kk] = fmaf(e2,x,a2c[kk]);
      a3c[kk] = fmaf(e3,x,a3c[kk]);
    }
  }
  const float sbi = sb * ((deg>0)?1.f:0.f);
  U2 o0,o1,o2,o3;
  #pragma unroll
  for(int kk=0;kk<4;kk++){
    o0.s[kk]=f2b(fmaf(sa,a0c[kk],sbi));
    o1.s[kk]=f2b(fmaf(sa,a1c[kk],sbi));
    o2.s[kk]=f2b(fmaf(sa,a2c[kk],sbi));
    o3.s[kk]=f2b(fmaf(sa,a3c[kk],sbi));
  }
  *(uint2*)(Axg + ((size_t)node)*256            + lane*4) = o0.v;
  *(uint2*)(Axg + ((size_t)NN + node)*256       + lane*4) = o1.v;
  *(uint2*)(Axg + ((size_t)2*NN + node)*256     + lane*4) = o2.v;
  *(uint2*)(Axg + ((size_t)3*NN + node)*256     + lane*4) = o3.v;
}

// ---------------- rst GEMM: 512 threads, 128x256 tile, BK=32 (R13-verified best: 49.8us).
// 8 waves = 2x4, wave 64x64 acc[4][4]. gll16 + both-sides 4x16B XOR swizzle.
// Epilogue: Og overlay in two 128-col passes. ----
__global__ __launch_bounds__(512) void k_gemm3(const us16* __restrict__ Axg, const us16* __restrict__ Wb,
    const float* __restrict__ gbias, us16* __restrict__ rst,
    float* __restrict__ bn1_sum, float* __restrict__ bn1_sq)
{
  __shared__ us16 sm[17408];   // 34816 B; K-loop: As [128][32]=8KB, Bs [256][32]=16KB; epilogue Og overlay
  us16* As = sm;
  us16* Bs = sm + 4096;
  const int tid = threadIdx.x;
  const int row0 = blockIdx.x*128;
  const int hd   = blockIdx.y;
  const us16* A  = Axg + (size_t)hd*NN*256;
  const us16* Bf = Wb  + (size_t)hd*256*256;     // all 256 output cols of this head
  const int lane = tid&63, wv = tid>>6;          // 8 waves
  const int wm = wv&1, wn = wv>>1;               // wave tile: rows [wm*64,+64), cols [wn*64,+64)
  const int mrow = lane&15, g4 = lane>>4;
  const us16* sgA; const us16* sgB[2];
  us16 *sdA, *sdB[2];
  {
    int r = wv*16 + (lane>>2);
    int c = (lane&3) ^ (r&3);
    int ga = row0 + r; if(ga >= NN) ga = NN-1;   // clamp; dead rows masked in epilogue
    sgA = A + (size_t)ga*256 + c*8;
    sdA = As + wv*512;
    #pragma unroll
    for(int i=0;i<2;i++){
      int rb = wv*32 + i*16 + (lane>>2);
      int cbk = (lane&3) ^ (rb&3);
      sgB[i] = Bf + (size_t)rb*256 + cbk*8;
      sdB[i] = Bs + wv*1024 + i*512;
    }
  }
  f32x4 acc[4][4] = {};
  for(int k0=0; k0<256; k0+=32){
    if(k0) __syncthreads();              // WAR: prior mfma LDS reads done
    gll16(sgA + k0, sdA);
    gll16(sgB[0] + k0, sdB[0]);
    gll16(sgB[1] + k0, sdB[1]);
    __syncthreads();                     // drains vmcnt (LDS-DMA complete), tile visible
    short8 af[4], bfr[4];
    #pragma unroll
    for(int i=0;i<4;i++){
      int r = wm*64 + i*16 + mrow;
      af[i] = *(const short8*)&As[r*32 + ((g4 ^ (r&3))<<3)];
    }
    #pragma unroll
    for(int j=0;j<4;j++){
      int r = wn*64 + j*16 + mrow;
      bfr[j] = *(const short8*)&Bs[r*32 + ((g4 ^ (r&3))<<3)];
    }
    #pragma unroll
    for(int i=0;i<4;i++){
      #pragma unroll
      for(int j=0;j<4;j++)
        acc[i][j] = __builtin_amdgcn_mfma_f32_16x16x32_bf16(af[i], bfr[j], acc[i][j], 0, 0, 0);
    }
  }
  float gb[4];
  #pragma unroll
  for(int j=0;j<4;j++)
    gb[j] = gbias[hd*256 + wn*64 + j*16 + (lane&15)];
  us16* Og = sm;                         // [128][136] us16 overlay
  #pragma unroll
  for(int p=0; p<2; p++){                // two 128-col passes: cols [p*128, p*128+128)
    __syncthreads();                     // pass 0: LDS reads done; pass 1: WAR on Og
    if((wn>>1) == p){
      float cs[4]={}, cq[4]={};
      #pragma unroll
      for(int i=0;i<4;i++){
        #pragma unroll
        for(int j=0;j<4;j++){
          #pragma unroll
          for(int r=0;r<4;r++){
            int rl = wm*64 + i*16 + (lane>>4)*4 + r;
            float v = acc[i][j][r] + gb[j];
            v = v>0.f ? v : 0.f;
            Og[rl*136 + (wn&1)*64 + j*16 + (lane&15)] = f2b(v);
            if(row0 + rl < NN){ cs[j] += v; cq[j] += v*v; }
          }
        }
      }
      #pragma unroll
      for(int j=0;j<4;j++){
        cs[j] += __shfl_xor(cs[j],16,64); cs[j] += __shfl_xor(cs[j],32,64);
        cq[j] += __shfl_xor(cq[j],16,64); cq[j] += __shfl_xor(cq[j],32,64);
      }
      if(lane < 16){
        #pragma unroll
        for(int j=0;j<4;j++){
          int col = hd*256 + p*128 + (wn&1)*64 + j*16 + lane;
          atomicAdd(&bn1_sum[col], cs[j]);
          atomicAdd(&bn1_sq[col],  cq[j]);
        }
      }
    }
    __syncthreads();                     // Og complete for this pass
    #pragma unroll
    for(int i=0;i<4;i++){
      int idx = i*512 + tid;             // 2048 uint4 = 128 rows x 16 chunks
      int rowl = idx>>4, cq2 = idx&15;
      int g = row0 + rowl;
      if(g < NN)
        *(uint4*)(rst + (size_t)g*1024 + hd*256 + p*128 + cq2*8) = *(const uint4*)&Og[rowl*136 + cq2*8];
    }
  }
}

// ---------------- conv2 GEMM: wave=32rows x 96cols (acc[2][6]), register bn1 (a,b),
//   Bs via global_load_lds, [96][64] linear + both-sides 8-chunk XOR swizzle (2-way banks) ----------------
__global__ __launch_bounds__(256) void k_gemm2(
    const us16* __restrict__ rst, const us16* __restrict__ Wt,
    const float* __restrict__ bn1_sum, const float* __restrict__ bn1_sq,
    const float* __restrict__ bn1g, const float* __restrict__ bn1b,
    const float* __restrict__ b1, const float* __restrict__ b2, const float* __restrict__ b3,
    us16* __restrict__ y2, float* __restrict__ bn2_sum, float* __restrict__ bn2_sq)
{
  __shared__ us16 As[11520];              // [16][10][72] = 23040 B
  __shared__ us16 Bs[6144];               // [96][64] linear = 12288 B (one (kc,s) stage, swizzled)
  __shared__ float redS[32], redQ[32];
  const int tid = threadIdx.x;
  if(tid<32){ redS[tid]=0.f; redQ[tid]=0.f; }
  const int node0 = blockIdx.x*16;
  const int lane = tid&63, wv = tid>>6;
  const int mrow = lane&15, kg = (lane>>4)*8, g4 = lane>>4;
  const int csrc = (lane&7) ^ (lane>>3);
  const int brow_off = (lane>>3)*128 + csrc*8;   // within-issue source offset (us16)
  us16* bdst[3];
  const us16* bsrc[3];
  #pragma unroll
  for(int i=0;i<3;i++){
    bdst[i] = Bs + (i*4+wv)*512;          // wave-uniform LDS base
    bsrc[i] = Wt + (size_t)(i*4+wv)*8*128 + brow_off;
  }
  // zero halo slots: 16 nodes x {0,9} x 64 ci (persist across kc rounds)
  for(int idx=tid; idx<2048; idx+=256){
    int n = idx>>7, rem = idx&127, slot = (rem>>6)*9, ci = rem&63;
    As[n*720 + slot*72 + ci] = 0;
  }
  f32x4 acc[2][6] = {};
  for(int kc=0; kc<2; kc++){
    // per-thread bn1 (a,b) for its repack channel ci = kc*64 + (tid&63): f = ci*8 + t, t=0..7
    float ra[8], rb[8];
    {
      int f0 = (kc*64 + (tid&63))*8;
      float4 s0 = *(const float4*)(bn1_sum + f0), s1 = *(const float4*)(bn1_sum + f0 + 4);
      float4 q0 = *(const float4*)(bn1_sq  + f0), q1 = *(const float4*)(bn1_sq  + f0 + 4);
      float4 g0 = *(const float4*)(bn1g    + f0), g1 = *(const float4*)(bn1g    + f0 + 4);
      float4 h0 = *(const float4*)(bn1b    + f0), h1 = *(const float4*)(bn1b    + f0 + 4);
      const float* sp = (const float*)&s0; const float* qp = (const float*)&q0;
      const float* gp = (const float*)&g0; const float* hp = (const float*)&h0;
      #pragma unroll
      for(int t=0;t<8;t++){
        float sv = (t<4)? sp[t] : ((const float*)&s1)[t-4];
        float qv = (t<4)? qp[t] : ((const float*)&q1)[t-4];
        float gv = (t<4)? gp[t] : ((const float*)&g1)[t-4];
        float hv = (t<4)? hp[t] : ((const float*)&h1)[t-4];
        float m = sv*(1.f/20000.f);
        float v = qv*(1.f/20000.f) - m*m;
        float a = gv*rsqrtf(v + 1e-5f);
        ra[t] = a; rb[t] = hv - m*a;
      }
    }
    if(kc) __syncthreads();              // WAR: prior mfma reads done before overwriting As
    #pragma unroll
    for(int i=0;i<4;i++){
      int idx = i*256 + tid;             // 1024 = 16 nodes x 64 cil
      int n = idx>>6, cil = idx&63;
      int ci = kc*64 + cil;
      U4 in; in.v = *(const uint4*)(rst + (size_t)(node0+n)*1024 + ci*8);
      us16* p = &As[n*720 + 72 + cil];
      #pragma unroll
      for(int t=0;t<8;t++)
        p[t*72] = f2b(fmaf(ra[t], b2f(in.s[t]), rb[t]));
    }
    for(int s=0; s<3; s++){
      if(s) __syncthreads();             // WAR for Bs between s rounds
      #pragma unroll
      for(int i=0;i<3;i++)
        gll16(bsrc[i] + s*12288 + kc*64, bdst[i]);
      __syncthreads();                   // drains vmcnt; RAW (covers As repack at s==0)
      #pragma unroll
      for(int kk=0; kk<64; kk+=32){
        short8 af[2], bfr[6];
        #pragma unroll
        for(int i=0;i<2;i++){
          int r = wv*32 + i*16 + mrow;
          af[i] = *(const short8*)&As[(r>>3)*720 + ((r&7)+s)*72 + kk + kg];
        }
        #pragma unroll
        for(int j=0;j<6;j++){
          int r = j*16 + mrow;
          int q = (kk>>3) + g4;
          bfr[j] = *(const short8*)&Bs[r*64 + ((q ^ (r&7))<<3)];
        }
        #pragma unroll
        for(int i=0;i<2;i++){
          #pragma unroll
          for(int j=0;j<6;j++)
            acc[i][j] = __builtin_amdgcn_mfma_f32_16x16x32_bf16(af[i], bfr[j], acc[i][j], 0, 0, 0);
        }
      }
    }
  }
  __syncthreads();                       // As/Bs dead; overlay output staging
  us16* Og = (us16*)As;                  // [16 nodes][32 co][8 t] us16 = 8192 B
  const int coA = lane&15, coB = coA+16;
  const float b1A=b1[coA], b2A=b2[coA], b3A=b3[coA];
  const float b1B=b1[coB], b2B=b2[coB], b3B=b3[coB];
  float sA=0.f, qA=0.f, sB=0.f, qB=0.f;
  const int g = lane>>4;
  #pragma unroll
  for(int i=0;i<2;i++){
    int node = wv*4 + i*2 + (g>>1);
    int t0 = (g&1)*4;
    U2 pA, pB;
    #pragma unroll
    for(int r=0;r<4;r++){
      float c1 = acc[i][0][r]+b1A, c2 = acc[i][2][r]+b2A, c3 = acc[i][4][r]+b3A;
      float sg = 1.f/(1.f+__expf(-c2));
      float v = fmaf(c1,sg,c3); v = v>0.f ? v : 0.f;
      sA += v; qA += v*v; pA.s[r]=f2b(v);
      c1 = acc[i][1][r]+b1B; c2 = acc[i][3][r]+b2B; c3 = acc[i][5][r]+b3B;
      sg = 1.f/(1.f+__expf(-c2));
      v = fmaf(c1,sg,c3); v = v>0.f ? v : 0.f;
      sB += v; qB += v*v; pB.s[r]=f2b(v);
    }
    *(uint2*)&Og[node*256 + coA*8 + t0] = pA.v;
    *(uint2*)&Og[node*256 + coB*8 + t0] = pB.v;
  }
  sA += __shfl_xor(sA,16,64); sA += __shfl_xor(sA,32,64);
  qA += __shfl_xor(qA,16,64); qA += __shfl_xor(qA,32,64);
  sB += __shfl_xor(sB,16,64); sB += __shfl_xor(sB,32,64);
  qB += __shfl_xor(qB,16,64); qB += __shfl_xor(qB,32,64);
  if(lane < 16){
    atomicAdd(&redS[coA], sA); atomicAdd(&redQ[coA], qA);
    atomicAdd(&redS[coB], sB); atomicAdd(&redQ[coB], qB);
  }
  __syncthreads();
  #pragma unroll
  for(int i=0;i<2;i++){
    int idx = i*256 + tid;                // 512 uint4
    *(uint4*)(y2 + (size_t)node0*256 + (size_t)idx*8) = *(const uint4*)&Og[idx*8];
  }
  if(tid<32)      atomicAdd(&bn2_sum[tid], redS[tid]);
  else if(tid<64) atomicAdd(&bn2_sq[tid-32], redQ[tid-32]);
}

// ---------------- final ----------------
__global__ __launch_bounds__(256) void k_final(const us16* __restrict__ y2,
    const float* __restrict__ bn2_sum, const float* __restrict__ bn2_sq,
    const float* __restrict__ bn2g, const float* __restrict__ bn2b,
    const us16* __restrict__ resid, float* __restrict__ out)
{
  __shared__ float fa[32], fb[32];
  const int tid = threadIdx.x;
  if(tid<32){
    float m = bn2_sum[tid]*(1.f/160000.f);
    float v = bn2_sq[tid]*(1.f/160000.f) - m*m;
    float a = bn2g[tid]*rsqrtf(v + 1e-5f);
    fa[tid] = a; fb[tid] = bn2b[tid] - m*a;
  }
  __syncthreads();
  size_t base = ((size_t)blockIdx.x*256 + tid)*8;
  int ch = (int)((base>>3)&31);
  float a = fa[ch], b = fb[ch];
  U4 yv, rv;
  yv.v = *(const uint4*)(y2+base);
  rv.v = *(const uint4*)(resid+base);
  float4 o0, o1;
  float vv[8];
  #pragma unroll
  for(int j=0;j<8;j++){
    float v = fmaf(a, b2f(yv.s[j]), b) + b2f(rv.s[j]);
    vv[j] = v>0.f ? v : 0.f;
  }
  o0.x=vv[0]; o0.y=vv[1]; o0.z=vv[2]; o0.w=vv[3];
  o1.x=vv[4]; o1.y=vv[5]; o1.z=vv[6]; o1.w=vv[7];
  *(float4*)(out+base)   = o0;
  *(float4*)(out+base+4) = o1;
}

extern "C" void kernel_launch(void* const* d_in, const int* in_sizes, int n_in,
                              void* d_out, int out_size, void* d_ws, size_t ws_size,
                              hipStream_t stream)
{
  const float* X    = (const float*)d_in[0];
  const int*  src   = (const int*)d_in[1];
  const int*  dst   = (const int*)d_in[2];
  const float* rp_w = (const float*)d_in[3];
  const float* rp_b = (const float*)d_in[4];
  const float* g1w1 = (const float*)d_in[5];
  const float* g1b1 = (const float*)d_in[6];
  const float* g1w2 = (const float*)d_in[7];
  const float* g1b2 = (const float*)d_in[8];
  const float* g1w3 = (const float*)d_in[9];
  const float* g1b3 = (const float*)d_in[10];
  const float* bn0g = (const float*)d_in[11];
  const float* bn0b = (const float*)d_in[12];
  const float* gatw = (const float*)d_in[13];
  const float* attnl= (const float*)d_in[14];
  const float* attnr= (const float*)d_in[15];
  const float* gbias= (const float*)d_in[16];
  const float* bn1g = (const float*)d_in[17];
  const float* bn1b = (const float*)d_in[18];
  const float* g2w1 = (const float*)d_in[19];
  const float* g2b1 = (const float*)d_in[20];
  const float* g2w2 = (const float*)d_in[21];
  const float* g2b2 = (const float*)d_in[22];
  const float* g2w3 = (const float*)d_in[23];
  const float* g2b3 = (const float*)d_in[24];
  const float* bn2g = (const float*)d_in[25];
  const float* bn2b = (const float*)d_in[26];
  float* out = (float*)d_out;
  (void)in_sizes; (void)n_in; (void)out_size; (void)ws_size;

  char* w = (char*)d_ws;
  float* bn0_sum = (float*)w;                 // 32
  float* bn0_sq  = bn0_sum + 32;              // 32
  float* bn1_sum = bn0_sum + 64;              // 1024
  float* bn1_sq  = bn1_sum + 1024;            // 1024
  float* bn2_sum = bn1_sq  + 1024;            // 32
  float* bn2_sq  = bn2_sum + 32;              // 32
  float* wl      = bn2_sq + 32;               // 1024 (zeroed: accumulated atomically)
  float* wr      = wl + 1024;                 // 1024
  int*   counts  = (int*)(wr + 1024);         // 20000
  size_t zeroBytes = (size_t)((char*)(counts + NN) - w);   // ~96.9 KB
  int*   offsets = counts + NN;               // 20004
  int*   cursor  = offsets + 20004;           // 20000
  int*   esrc    = cursor + NN;               // 320000
  float* el      = (float*)(esrc + NE);       // 80000
  float* er      = el + NN*4;                 // 80000
  float* ew      = er + NN*4;                 // 1,280,000
  us16*  wb      = (us16*)(ew + (size_t)NE*4);// 262144
  us16*  resid   = wb + 262144;               // 5,120,000
  us16*  gc1     = resid + 5120000;           // 5,120,000 (raw gated conv1)
  us16*  Axg     = gc1   + 5120000;           // 20,480,000  [hd][node][256]
  us16*  rst     = Axg   + 20480000;          // 20,480,000
  us16*  Wt      = rst   + 20480000;          // 36,864
  us16*  Wt1     = Wt    + 36864;             // 12,288
  us16*  y2      = gc1;                       // alias: gc1 dead after k_agg2

  hipMemsetAsync(d_ws, 0, zeroBytes, stream);
  k_misc<<<1730, 256, 0, stream>>>(gatw, wb, g2w1, g2w2, g2w3, Wt,
                                   g1w1, g1w2, g1w3, rp_w, Wt1,
                                   attnl, attnr, wl, wr, dst, counts);
  k_gemm1<<<1251, 256, 0, stream>>>(X, Wt1, g1b1, g1b2, g1b3, rp_b,
                                    gc1, resid, bn0_sum, bn0_sq,
                                    counts, offsets, cursor);
  k_eler2<<<5000, 256, 0, stream>>>(gc1, bn0_sum, bn0_sq, bn0g, bn0b, wl, wr, el, er);
  k_scatter<<<1250, 256, 0, stream>>>(src, dst, cursor, esrc, el, er, ew);
  k_agg2<<<5000, 256, 0, stream>>>(offsets, esrc, ew, gc1, bn0_sum, bn0_sq, bn0g, bn0b, Axg);
  k_gemm3<<<dim3(157, 4), 512, 0, stream>>>(Axg, wb, gbias, rst, bn1_sum, bn1_sq);
  k_gemm2<<<1250, 256, 0, stream>>>(rst, Wt, bn1_sum, bn1_sq, bn1g, bn1b,
                                    g2b1, g2b2, g2b3, y2, bn2_sum, bn2_sq);
  k_final<<<2500, 256, 0, stream>>>(y2, bn2_sum, bn2_sq, bn2g, bn2b, resid, out);
}

// Round 17
// 335.534 us; speedup vs baseline: 1.0440x; 1.0440x over previous
//
#include <hip/hip_runtime.h>
#include <stdint.h>

#define NN 20000
#define NE 320000

typedef unsigned short us16;
typedef __attribute__((ext_vector_type(8))) short short8;
typedef __attribute__((ext_vector_type(4))) float f32x4;

union U4 { uint4 v; us16 s[8]; unsigned u[4]; };
union U2 { uint2 v; us16 s[4]; };

__device__ __forceinline__ float b2f(us16 u){ return __uint_as_float(((unsigned)u)<<16); }
__device__ __forceinline__ us16 f2b(float f){
  unsigned u = __float_as_uint(f);
  u += 0x7fffu + ((u>>16)&1u);
  return (us16)(u>>16);
}

__device__ __forceinline__ void gll16(const void* g, void* l){
  __builtin_amdgcn_global_load_lds((const __attribute__((address_space(1))) void*)g,
                                   (__attribute__((address_space(3))) void*)l, 16, 0, 0);
}

// ---------------- merged misc: gat_w cvt + conv2 wprep + conv1 wprep + wl/wr + hist ----------------
__global__ __launch_bounds__(256) void k_misc(
    const float* __restrict__ gatw, us16* __restrict__ Wb,
    const float* __restrict__ w1, const float* __restrict__ w2, const float* __restrict__ w3,
    us16* __restrict__ Wt,
    const float* __restrict__ c1w1, const float* __restrict__ c1w2, const float* __restrict__ c1w3,
    const float* __restrict__ rp_w, us16* __restrict__ Wt1,
    const float* __restrict__ attnl, const float* __restrict__ attnr,
    float* __restrict__ wl, float* __restrict__ wr,
    const int* __restrict__ dst, int* __restrict__ counts)
{
  const int b = blockIdx.x, tid = threadIdx.x;
  if(b < 256){
    int i = b*256 + tid;
    float4 v = *(const float4*)(gatw + (size_t)i*4);
    U2 o;
    o.s[0]=f2b(v.x); o.s[1]=f2b(v.y); o.s[2]=f2b(v.z); o.s[3]=f2b(v.w);
    *(uint2*)(Wb + (size_t)i*4) = o.v;
  } else if(b < 400){
    int i = (b-256)*256 + tid;       // 36864: Wt[s][co3(96)][ci(128)]
    int s = i/12288, rem = i%12288;
    int co3 = rem>>7, ci = rem&127;
    const float* w = (co3<32) ? w1 : (co3<64) ? w2 : w3;
    Wt[i] = f2b(w[(co3&31)*384 + ci*3 + s]);
  } else if(b < 448){
    int i = (b-400)*256 + tid;       // 12288: Wt1[s][co3(128)][ci(32)]
    int s = i>>12, rem = i&4095;
    int co3 = rem>>5, ci = rem&31;
    float v;
    if(co3 < 96){
      const float* w = (co3<32) ? c1w1 : (co3<64) ? c1w2 : c1w3;
      v = w[(co3&31)*96 + ci*3 + s];
    } else {
      v = (s==1) ? rp_w[(co3-96)*32 + ci] : 0.f;
    }
    Wt1[i] = f2b(v);
  } else if(b < 480){
    int bb = b-448;                   // 0..31
    int sel = bb>>4, hd = (bb>>2)&3, fq = bb&3;
    const float* attn = sel ? attnr : attnl;
    int k = tid;
    float s = 0.f;
    int f0 = fq*64;
    #pragma unroll 8
    for(int f=f0; f<f0+64; f++)
      s = fmaf(attn[hd*256+f], gatw[(size_t)(hd*256+f)*256 + k], s);
    atomicAdd(&((sel ? wr : wl)[hd*256+k]), s);
  } else {
    int e = (b-480)*256 + tid;
    if(e < NE) atomicAdd(&counts[dst[e]], 1);
  }
}

// ---------------- conv1 (+residual k1) as MFMA GEMM + coalesced CSR scan tail block ----------------
__global__ __launch_bounds__(256) void k_gemm1(
    const float* __restrict__ X, const us16* __restrict__ Wt1,
    const float* __restrict__ b1, const float* __restrict__ b2, const float* __restrict__ b3,
    const float* __restrict__ rp_b,
    us16* __restrict__ gc1, us16* __restrict__ resid,
    float* __restrict__ bn0_sum, float* __restrict__ bn0_sq,
    const int* __restrict__ counts, int* __restrict__ offsets, int* __restrict__ cursor)
{
  __shared__ float smemF[5760];            // 23040 B: As 12800 B + Bs(one tap) 10240 B
  __shared__ float redS[32], redQ[32];
  __shared__ int wred[4];
  const int tid = threadIdx.x;
  if(blockIdx.x < 1250){
    us16* As = (us16*)smemF;                // [16][10][40] = 6400 us16
    us16* Bs = As + 6400;                   // [128][40]    = 5120 us16 (one tap)
    if(tid<32){ redS[tid]=0.f; redQ[tid]=0.f; }
    const int node0 = blockIdx.x*16;
    const int lane = tid&63, wv = tid>>6;
    const int mrow = lane&15, kg = (lane>>4)*8;
    for(int idx=tid; idx<1024; idx+=256){
      int n = idx>>6, rem = idx&63, slot = (rem>>5)*9, ci = rem&31;
      As[n*400 + slot*40 + ci] = 0;
    }
    #pragma unroll
    for(int i=0;i<4;i++){
      int idx = i*256 + tid;
      int n = idx>>6, rem = idx&63, ci = rem>>1, tq = rem&1;
      float4 xv = *(const float4*)(X + (size_t)(node0+n)*256 + ci*8 + tq*4);
      us16* p = &As[n*400 + (tq*4+1)*40 + ci];
      p[0]   = f2b(xv.x);
      p[40]  = f2b(xv.y);
      p[80]  = f2b(xv.z);
      p[120] = f2b(xv.w);
    }
    f32x4 acc[2][8] = {};
    for(int s=0; s<3; s++){
      if(s) __syncthreads();               // WAR: prior tap's mfma reads done before overwrite
      #pragma unroll
      for(int i=0;i<2;i++){
        int c = i*256 + tid;               // 512 uint4 = 128 co x 4 chunks
        int co = c>>2, cq = c&3;
        *(uint4*)&Bs[co*40 + cq*8] = *(const uint4*)(Wt1 + s*4096 + co*32 + cq*8);
      }
      __syncthreads();                     // covers As staging too (s==0)
      short8 af[2], bfr[8];
      #pragma unroll
      for(int i=0;i<2;i++){
        int r = wv*32 + i*16 + mrow;
        af[i] = *(const short8*)&As[(r>>3)*400 + ((r&7)+s)*40 + kg];
      }
      #pragma unroll
      for(int j=0;j<8;j++)
        bfr[j] = *(const short8*)&Bs[(j*16 + mrow)*40 + kg];
      #pragma unroll
      for(int i=0;i<2;i++){
        #pragma unroll
        for(int j=0;j<8;j++)
          acc[i][j] = __builtin_amdgcn_mfma_f32_16x16x32_bf16(af[i], bfr[j], acc[i][j], 0, 0, 0);
      }
    }
    __syncthreads();                        // As/Bs dead; overlay output staging
    us16* Og = (us16*)smemF;                // [16 nodes][32 co][8 t] us16 = 8192 B
    us16* Or = Og + 4096;                   // 8192 B
    const int coA = lane&15, coB = coA+16;
    const float b1A=b1[coA], b2A=b2[coA], b3A=b3[coA], brA=rp_b[coA];
    const float b1B=b1[coB], b2B=b2[coB], b3B=b3[coB], brB=rp_b[coB];
    float sA=0.f, qA=0.f, sB=0.f, qB=0.f;
    const int g = lane>>4;
    #pragma unroll
    for(int i=0;i<2;i++){
      int node = wv*4 + i*2 + (g>>1);
      int t0 = (g&1)*4;
      U2 pA, pB, rA2, rB2;
      #pragma unroll
      for(int r=0;r<4;r++){
        float c1 = acc[i][0][r]+b1A, c2 = acc[i][2][r]+b2A, c3 = acc[i][4][r]+b3A;
        float rr = acc[i][6][r]+brA;
        float sg = 1.f/(1.f+__expf(-c2));
        float v = fmaf(c1,sg,c3); v = v>0.f ? v : 0.f;
        sA += v; qA += v*v;
        pA.s[r]=f2b(v); rA2.s[r]=f2b(rr);
        c1 = acc[i][1][r]+b1B; c2 = acc[i][3][r]+b2B; c3 = acc[i][5][r]+b3B;
        rr = acc[i][7][r]+brB;
        sg = 1.f/(1.f+__expf(-c2));
        v = fmaf(c1,sg,c3); v = v>0.f ? v : 0.f;
        sB += v; qB += v*v;
        pB.s[r]=f2b(v); rB2.s[r]=f2b(rr);
      }
      *(uint2*)&Og[node*256 + coA*8 + t0] = pA.v;
      *(uint2*)&Og[node*256 + coB*8 + t0] = pB.v;
      *(uint2*)&Or[node*256 + coA*8 + t0] = rA2.v;
      *(uint2*)&Or[node*256 + coB*8 + t0] = rB2.v;
    }
    sA += __shfl_xor(sA,16,64); sA += __shfl_xor(sA,32,64);
    qA += __shfl_xor(qA,16,64); qA += __shfl_xor(qA,32,64);
    sB += __shfl_xor(sB,16,64); sB += __shfl_xor(sB,32,64);
    qB += __shfl_xor(qB,16,64); qB += __shfl_xor(qB,32,64);
    if(lane < 16){
      atomicAdd(&redS[coA], sA); atomicAdd(&redQ[coA], qA);
      atomicAdd(&redS[coB], sB); atomicAdd(&redQ[coB], qB);
    }
    __syncthreads();
    #pragma unroll
    for(int i=0;i<2;i++){
      int idx = i*256 + tid;                // 512 uint4 each
      *(uint4*)(gc1   + (size_t)node0*256 + (size_t)idx*8) = *(const uint4*)&Og[idx*8];
      *(uint4*)(resid + (size_t)node0*256 + (size_t)idx*8) = *(const uint4*)&Or[idx*8];
    }
    if(tid<32)      atomicAdd(&bn0_sum[tid], redS[tid]);
    else if(tid<64) atomicAdd(&bn0_sq[tid-32], redQ[tid-32]);
  } else {
    // ---- CSR exclusive scan: tiled (1024/tile), wave shfl scan, coalesced int4 I/O ----
    const int lane = tid&63, wv = tid>>6;
    int running = 0;
    int4 cur;
    {
      int idx = tid*4;
      cur = *(const int4*)(counts + idx);
    }
    for(int t=0; t<20; t++){
      int4 nxt; nxt.x=0; nxt.y=0; nxt.z=0; nxt.w=0;
      if(t < 19){
        int idx = (t+1)*1024 + tid*4;
        if(idx+3 < NN) nxt = *(const int4*)(counts + idx);
        else {
          if(idx   < NN) nxt.x = counts[idx];
          if(idx+1 < NN) nxt.y = counts[idx+1];
          if(idx+2 < NN) nxt.z = counts[idx+2];
          if(idx+3 < NN) nxt.w = counts[idx+3];
        }
      }
      int s = cur.x + cur.y + cur.z + cur.w;
      int incl = s;
      #pragma unroll
      for(int off=1; off<64; off<<=1){
        int v = __shfl_up(incl, off, 64);
        if(lane >= off) incl += v;
      }
      if(lane==63) wred[wv] = incl;
      __syncthreads();
      int woff = 0, btot = 0;
      #pragma unroll
      for(int w2=0; w2<4; w2++){
        int x = wred[w2];
        btot += x;
        if(w2 < wv) woff += x;
      }
      int e0 = running + woff + incl - s;
      int idx = t*1024 + tid*4;
      int4 o; o.x=e0; o.y=e0+cur.x; o.z=o.y+cur.y; o.w=o.z+cur.z;
      if(idx+3 < NN){
        *(int4*)(offsets+idx) = o;
        *(int4*)(cursor+idx)  = o;
      } else {
        if(idx   < NN){ offsets[idx]  =o.x; cursor[idx]  =o.x; }
        if(idx+1 < NN){ offsets[idx+1]=o.y; cursor[idx+1]=o.y; }
        if(idx+2 < NN){ offsets[idx+2]=o.z; cursor[idx+2]=o.z; }
        if(idx+3 < NN){ offsets[idx+3]=o.w; cursor[idx+3]=o.w; }
      }
      running += btot;
      cur = nxt;
      __syncthreads();
    }
    if(tid==0) offsets[NN] = running;
  }
}

// ---------------- el/er from gc1 (bn0 folded): wave per node ----------------
__global__ __launch_bounds__(256) void k_eler2(const us16* __restrict__ gc1,
    const float* __restrict__ bn0_sum, const float* __restrict__ bn0_sq,
    const float* __restrict__ bn0g, const float* __restrict__ bn0b,
    const float* __restrict__ wl, const float* __restrict__ wr,
    float* __restrict__ el, float* __restrict__ er)
{
  __shared__ float sa[32], sb[32];
  const int tid = threadIdx.x;
  if(tid<32){
    float m = bn0_sum[tid]*(1.f/160000.f);
    float v = bn0_sq[tid]*(1.f/160000.f) - m*m;
    float a = bn0g[tid]*rsqrtf(v + 1e-5f);
    sa[tid] = a; sb[tid] = bn0b[tid] - m*a;
  }
  __syncthreads();
  const int wv = tid>>6, lane = tid&63;
  const int node = blockIdx.x*4 + wv;
  U2 g; g.v = *(const uint2*)(gc1 + (size_t)node*256 + lane*4);
  const float a = sa[lane>>1], b = sb[lane>>1];
  float xv[4];
  #pragma unroll
  for(int j=0;j<4;j++) xv[j] = fmaf(a, b2f(g.s[j]), b);
  float res[8];
  #pragma unroll
  for(int hd=0; hd<4; hd++){
    float4 lv = *(const float4*)(wl + hd*256 + lane*4);
    float4 rv = *(const float4*)(wr + hd*256 + lane*4);
    res[hd]   = xv[0]*lv.x + xv[1]*lv.y + xv[2]*lv.z + xv[3]*lv.w;
    res[4+hd] = xv[0]*rv.x + xv[1]*rv.y + xv[2]*rv.z + xv[3]*rv.w;
  }
  #pragma unroll
  for(int o=32;o;o>>=1){
    #pragma unroll
    for(int k=0;k<8;k++) res[k] += __shfl_xor(res[k], o, 64);
  }
  if(lane==0){
    #pragma unroll
    for(int hd=0;hd<4;hd++){ el[node*4+hd]=res[hd]; er[node*4+hd]=res[4+hd]; }
  }
}

// ---------------- scatter + edge scores ----------------
__global__ __launch_bounds__(256) void k_scatter(const int* __restrict__ src, const int* __restrict__ dst,
    int* __restrict__ cursor, int* __restrict__ esrc,
    const float* __restrict__ el, const float* __restrict__ er,
    float* __restrict__ ew)
{
  int e = blockIdx.x*256 + threadIdx.x;
  if(e < NE){
    int s = src[e], d = dst[e];
    int pos = atomicAdd(&cursor[d], 1);
    esrc[pos] = s;
    float4 lv = *(const float4*)(el + s*4);
    float4 rv = *(const float4*)(er + d*4);
    float4 sc;
    sc.x = lv.x+rv.x; sc.x = sc.x>0.f ? sc.x : 0.2f*sc.x;
    sc.y = lv.y+rv.y; sc.y = sc.y>0.f ? sc.y : 0.2f*sc.y;
    sc.z = lv.z+rv.z; sc.z = sc.z>0.f ? sc.z : 0.2f*sc.z;
    sc.w = lv.w+rv.w; sc.w = sc.w>0.f ? sc.w : 0.2f*sc.w;
    *(float4*)(ew + (size_t)pos*4) = sc;
  }
}

// ---------------- GAT aggregate in x-space: one wave per node, no LDS, no barriers ----------------
__global__ __launch_bounds__(256) void k_agg2(
    const int* __restrict__ offsets, const int* __restrict__ esrc,
    const float* __restrict__ ew, const us16* __restrict__ gc1,
    const float* __restrict__ bn0_sum, const float* __restrict__ bn0_sq,
    const float* __restrict__ bn0g, const float* __restrict__ bn0b,
    us16* __restrict__ Axg)
{
  const int tid = threadIdx.x;
  const int wv = tid>>6, lane = tid&63;
  const int node = blockIdx.x*4 + wv;
  const int ch = lane>>1;
  float mmn = bn0_sum[ch]*(1.f/160000.f);
  float vvn = bn0_sq[ch]*(1.f/160000.f) - mmn*mmn;
  float sa = bn0g[ch]*rsqrtf(vvn + 1e-5f);
  float sb = bn0b[ch] - mmn*sa;
  const int beg = offsets[node];
  const int deg = offsets[node+1] - beg;
  const int h = lane>>4, i0 = lane&15;
  float m = -3.0e38f;
  for(int i=i0; i<deg; i+=16) m = fmaxf(m, ew[(size_t)(beg+i)*4 + h]);
  m = fmaxf(m, __shfl_xor(m,1,64)); m = fmaxf(m, __shfl_xor(m,2,64));
  m = fmaxf(m, __shfl_xor(m,4,64)); m = fmaxf(m, __shfl_xor(m,8,64));
  float den = 0.f;
  for(int i=i0; i<deg; i+=16) den += __expf(ew[(size_t)(beg+i)*4 + h] - m);
  den += __shfl_xor(den,1,64); den += __shfl_xor(den,2,64);
  den += __shfl_xor(den,4,64); den += __shfl_xor(den,8,64);
  const float m0=__shfl(m,0,64),   m1=__shfl(m,16,64),  m2=__shfl(m,32,64),  m3=__shfl(m,48,64);
  const float d0=__shfl(den,0,64), d1=__shfl(den,16,64),d2=__shfl(den,32,64),d3=__shfl(den,48,64);
  const float v0=d0>0.f?1.f/d0:0.f, v1=d1>0.f?1.f/d1:0.f,
              v2=d2>0.f?1.f/d2:0.f, v3=d3>0.f?1.f/d3:0.f;
  float a0c[4]={},a1c[4]={},a2c[4]={},a3c[4]={};
  #pragma unroll 4
  for(int j=0; j<deg; j++){
    int pos = beg+j;
    float4 w4 = *(const float4*)(ew + (size_t)pos*4);
    int sN = esrc[pos];
    U2 hv; hv.v = *(const uint2*)(gc1 + (size_t)sN*256 + lane*4);
    float e0 = __expf(w4.x-m0)*v0;
    float e1 = __expf(w4.y-m1)*v1;
    float e2 = __expf(w4.z-m2)*v2;
    float e3 = __expf(w4.w-m3)*v3;
    #pragma unroll
    for(int kk=0;kk<4;kk++){
      float x = b2f(hv.s[kk]);
      a0c[kk] = fmaf(e0,x,a0c[kk]);
      a1c[kk] = fmaf(e1,x,a1c[kk]);
      a2c[kk] = fmaf(e2,x,a2c[kk]);
      a3c[kk] = fmaf(e3,x,a3c[kk]);
    }
  }
  const float sbi = sb * ((deg>0)?1.f:0.f);
  U2 o0,o1,o2,o3;
  #pragma unroll
  for(int kk=0;kk<4;kk++){
    o0.s[kk]=f2b(fmaf(sa,a0c[kk],sbi));
    o1.s[kk]=f2b(fmaf(sa,a1c[kk],sbi));
    o2.s[kk]=f2b(fmaf(sa,a2c[kk],sbi));
    o3.s[kk]=f2b(fmaf(sa,a3c[kk],sbi));
  }
  *(uint2*)(Axg + ((size_t)node)*256            + lane*4) = o0.v;
  *(uint2*)(Axg + ((size_t)NN + node)*256       + lane*4) = o1.v;
  *(uint2*)(Axg + ((size_t)2*NN + node)*256     + lane*4) = o2.v;
  *(uint2*)(Axg + ((size_t)3*NN + node)*256     + lane*4) = o3.v;
}

// ---------------- rst GEMM: 512 threads, 128x256 tile, BK=32, T4 counted-vmcnt pipeline.
// Double-buffered gll16; raw s_barrier (no vmcnt(0) drain); per-wave vmcnt(3) lets the next
// tile's 3 loads fly across the barrier (m201 pattern). 8 waves 2x4, wave 64x64 acc[4][4].
// Both-sides 4x16B XOR swizzle. Epilogue: Og overlay in two 128-col passes. ----
__global__ __launch_bounds__(512) void k_gemm3(const us16* __restrict__ Axg, const us16* __restrict__ Wb,
    const float* __restrict__ gbias, us16* __restrict__ rst,
    float* __restrict__ bn1_sum, float* __restrict__ bn1_sq)
{
  __shared__ us16 sm[24576];   // 49152 B: As dbuf 2x[128][32], Bs dbuf 2x[256][32]; epilogue overlay
  const int tid = threadIdx.x;
  const int row0 = blockIdx.x*128;
  const int hd   = blockIdx.y;
  const us16* A  = Axg + (size_t)hd*NN*256;
  const us16* Bf = Wb  + (size_t)hd*256*256;     // all 256 output cols of this head
  const int lane = tid&63, wv = tid>>6;          // 8 waves
  const int wm = wv&1, wn = wv>>1;               // wave tile: rows [wm*64,+64), cols [wn*64,+64)
  const int mrow = lane&15, g4 = lane>>4;
  const us16* sgA; const us16* sgB[2];
  us16 *sdA, *sdB[2];
  {
    int r = wv*16 + (lane>>2);
    int c = (lane&3) ^ (r&3);
    int ga = row0 + r; if(ga >= NN) ga = NN-1;   // clamp; dead rows masked in epilogue
    sgA = A + (size_t)ga*256 + c*8;
    sdA = sm + wv*512;                            // As buf0 base
    #pragma unroll
    for(int i=0;i<2;i++){
      int rb = wv*32 + i*16 + (lane>>2);
      int cbk = (lane&3) ^ (rb&3);
      sgB[i] = Bf + (size_t)rb*256 + cbk*8;
      sdB[i] = sm + 8192 + wv*1024 + i*512;       // Bs buf0 base
    }
  }
  // prologue: stage tiles 0 (buf0) and 1 (buf1); 6 loads in flight
  gll16(sgA,        sdA);
  gll16(sgB[0],     sdB[0]);
  gll16(sgB[1],     sdB[1]);
  gll16(sgA + 32,   sdA + 4096);
  gll16(sgB[0] + 32, sdB[0] + 8192);
  gll16(sgB[1] + 32, sdB[1] + 8192);
  f32x4 acc[4][4] = {};
  for(int it=0; it<8; ++it){
    // wait ONLY for this tile's 3 loads (oldest); next tile's 3 stay in flight
    if(it < 7) asm volatile("s_waitcnt vmcnt(3)" ::: "memory");
    else       asm volatile("s_waitcnt vmcnt(0)" ::: "memory");
    __builtin_amdgcn_s_barrier();        // all waves' tile-it stages visible
    const us16* Ac = sm + (it&1)*4096;
    const us16* Bc = sm + 8192 + (it&1)*8192;
    short8 af[4], bfr[4];
    #pragma unroll
    for(int i=0;i<4;i++){
      int r = wm*64 + i*16 + mrow;
      af[i] = *(const short8*)&Ac[r*32 + ((g4 ^ (r&3))<<3)];
    }
    #pragma unroll
    for(int j=0;j<4;j++){
      int r = wn*64 + j*16 + mrow;
      bfr[j] = *(const short8*)&Bc[r*32 + ((g4 ^ (r&3))<<3)];
    }
    #pragma unroll
    for(int i=0;i<4;i++){
      #pragma unroll
      for(int j=0;j<4;j++)
        acc[i][j] = __builtin_amdgcn_mfma_f32_16x16x32_bf16(af[i], bfr[j], acc[i][j], 0, 0, 0);
    }
    __builtin_amdgcn_s_barrier();        // all waves done reading buf[it&1]
    if(it < 6){
      int k0 = (it+2)*32;                // stage tile it+2 into buf[it&1] (now free)
      gll16(sgA + k0,    sdA + (it&1)*4096);
      gll16(sgB[0] + k0, sdB[0] + (it&1)*8192);
      gll16(sgB[1] + k0, sdB[1] + (it&1)*8192);
    }
  }
  float gb[4];
  #pragma unroll
  for(int j=0;j<4;j++)
    gb[j] = gbias[hd*256 + wn*64 + j*16 + (lane&15)];
  us16* Og = sm;                         // [128][136] us16 overlay
  #pragma unroll
  for(int p=0; p<2; p++){                // two 128-col passes: cols [p*128, p*128+128)
    __syncthreads();                     // pass 0: LDS reads done; pass 1: WAR on Og
    if((wn>>1) == p){
      float cs[4]={}, cq[4]={};
      #pragma unroll
      for(int i=0;i<4;i++){
        #pragma unroll
        for(int j=0;j<4;j++){
          #pragma unroll
          for(int r=0;r<4;r++){
            int rl = wm*64 + i*16 + (lane>>4)*4 + r;
            float v = acc[i][j][r] + gb[j];
            v = v>0.f ? v : 0.f;
            Og[rl*136 + (wn&1)*64 + j*16 + (lane&15)] = f2b(v);
            if(row0 + rl < NN){ cs[j] += v; cq[j] += v*v; }
          }
        }
      }
      #pragma unroll
      for(int j=0;j<4;j++){
        cs[j] += __shfl_xor(cs[j],16,64); cs[j] += __shfl_xor(cs[j],32,64);
        cq[j] += __shfl_xor(cq[j],16,64); cq[j] += __shfl_xor(cq[j],32,64);
      }
      if(lane < 16){
        #pragma unroll
        for(int j=0;j<4;j++){
          int col = hd*256 + p*128 + (wn&1)*64 + j*16 + lane;
          atomicAdd(&bn1_sum[col], cs[j]);
          atomicAdd(&bn1_sq[col],  cq[j]);
        }
      }
    }
    __syncthreads();                     // Og complete for this pass
    #pragma unroll
    for(int i=0;i<4;i++){
      int idx = i*512 + tid;             // 2048 uint4 = 128 rows x 16 chunks
      int rowl = idx>>4, cq2 = idx&15;
      int g = row0 + rowl;
      if(g < NN)
        *(uint4*)(rst + (size_t)g*1024 + hd*256 + p*128 + cq2*8) = *(const uint4*)&Og[rowl*136 + cq2*8];
    }
  }
}

// ---------------- conv2 GEMM: wave=32rows x 96cols (acc[2][6]), register bn1 (a,b),
//   Bs via global_load_lds, [96][64] linear + both-sides 8-chunk XOR swizzle (2-way banks) ----------------
__global__ __launch_bounds__(256) void k_gemm2(
    const us16* __restrict__ rst, const us16* __restrict__ Wt,
    const float* __restrict__ bn1_sum, const float* __restrict__ bn1_sq,
    const float* __restrict__ bn1g, const float* __restrict__ bn1b,
    const float* __restrict__ b1, const float* __restrict__ b2, const float* __restrict__ b3,
    us16* __restrict__ y2, float* __restrict__ bn2_sum, float* __restrict__ bn2_sq)
{
  __shared__ us16 As[11520];              // [16][10][72] = 23040 B
  __shared__ us16 Bs[6144];               // [96][64] linear = 12288 B (one (kc,s) stage, swizzled)
  __shared__ float redS[32], redQ[32];
  const int tid = threadIdx.x;
  if(tid<32){ redS[tid]=0.f; redQ[tid]=0.f; }
  const int node0 = blockIdx.x*16;
  const int lane = tid&63, wv = tid>>6;
  const int mrow = lane&15, kg = (lane>>4)*8, g4 = lane>>4;
  const int csrc = (lane&7) ^ (lane>>3);
  const int brow_off = (lane>>3)*128 + csrc*8;   // within-issue source offset (us16)
  us16* bdst[3];
  const us16* bsrc[3];
  #pragma unroll
  for(int i=0;i<3;i++){
    bdst[i] = Bs + (i*4+wv)*512;          // wave-uniform LDS base
    bsrc[i] = Wt + (size_t)(i*4+wv)*8*128 + brow_off;
  }
  // zero halo slots: 16 nodes x {0,9} x 64 ci (persist across kc rounds)
  for(int idx=tid; idx<2048; idx+=256){
    int n = idx>>7, rem = idx&127, slot = (rem>>6)*9, ci = rem&63;
    As[n*720 + slot*72 + ci] = 0;
  }
  f32x4 acc[2][6] = {};
  for(int kc=0; kc<2; kc++){
    // per-thread bn1 (a,b) for its repack channel ci = kc*64 + (tid&63): f = ci*8 + t, t=0..7
    float ra[8], rb[8];
    {
      int f0 = (kc*64 + (tid&63))*8;
      float4 s0 = *(const float4*)(bn1_sum + f0), s1 = *(const float4*)(bn1_sum + f0 + 4);
      float4 q0 = *(const float4*)(bn1_sq  + f0), q1 = *(const float4*)(bn1_sq  + f0 + 4);
      float4 g0 = *(const float4*)(bn1g    + f0), g1 = *(const float4*)(bn1g    + f0 + 4);
      float4 h0 = *(const float4*)(bn1b    + f0), h1 = *(const float4*)(bn1b    + f0 + 4);
      const float* sp = (const float*)&s0; const float* qp = (const float*)&q0;
      const float* gp = (const float*)&g0; const float* hp = (const float*)&h0;
      #pragma unroll
      for(int t=0;t<8;t++){
        float sv = (t<4)? sp[t] : ((const float*)&s1)[t-4];
        float qv = (t<4)? qp[t] : ((const float*)&q1)[t-4];
        float gv = (t<4)? gp[t] : ((const float*)&g1)[t-4];
        float hv = (t<4)? hp[t] : ((const float*)&h1)[t-4];
        float m = sv*(1.f/20000.f);
        float v = qv*(1.f/20000.f) - m*m;
        float a = gv*rsqrtf(v + 1e-5f);
        ra[t] = a; rb[t] = hv - m*a;
      }
    }
    if(kc) __syncthreads();              // WAR: prior mfma reads done before overwriting As
    #pragma unroll
    for(int i=0;i<4;i++){
      int idx = i*256 + tid;             // 1024 = 16 nodes x 64 cil
      int n = idx>>6, cil = idx&63;
      int ci = kc*64 + cil;
      U4 in; in.v = *(const uint4*)(rst + (size_t)(node0+n)*1024 + ci*8);
      us16* p = &As[n*720 + 72 + cil];
      #pragma unroll
      for(int t=0;t<8;t++)
        p[t*72] = f2b(fmaf(ra[t], b2f(in.s[t]), rb[t]));
    }
    for(int s=0; s<3; s++){
      if(s) __syncthreads();             // WAR for Bs between s rounds
      #pragma unroll
      for(int i=0;i<3;i++)
        gll16(bsrc[i] + s*12288 + kc*64, bdst[i]);
      __syncthreads();                   // drains vmcnt; RAW (covers As repack at s==0)
      #pragma unroll
      for(int kk=0; kk<64; kk+=32){
        short8 af[2], bfr[6];
        #pragma unroll
        for(int i=0;i<2;i++){
          int r = wv*32 + i*16 + mrow;
          af[i] = *(const short8*)&As[(r>>3)*720 + ((r&7)+s)*72 + kk + kg];
        }
        #pragma unroll
        for(int j=0;j<6;j++){
          int r = j*16 + mrow;
          int q = (kk>>3) + g4;
          bfr[j] = *(const short8*)&Bs[r*64 + ((q ^ (r&7))<<3)];
        }
        #pragma unroll
        for(int i=0;i<2;i++){
          #pragma unroll
          for(int j=0;j<6;j++)
            acc[i][j] = __builtin_amdgcn_mfma_f32_16x16x32_bf16(af[i], bfr[j], acc[i][j], 0, 0, 0);
        }
      }
    }
  }
  __syncthreads();                       // As/Bs dead; overlay output staging
  us16* Og = (us16*)As;                  // [16 nodes][32 co][8 t] us16 = 8192 B
  const int coA = lane&15, coB = coA+16;
  const float b1A=b1[coA], b2A=b2[coA], b3A=b3[coA];
  const float b1B=b1[coB], b2B=b2[coB], b3B=b3[coB];
  float sA=0.f, qA=0.f, sB=0.f, qB=0.f;
  const int g = lane>>4;
  #pragma unroll
  for(int i=0;i<2;i++){
    int node = wv*4 + i*2 + (g>>1);
    int t0 = (g&1)*4;
    U2 pA, pB;
    #pragma unroll
    for(int r=0;r<4;r++){
      float c1 = acc[i][0][r]+b1A, c2 = acc[i][2][r]+b2A, c3 = acc[i][4][r]+b3A;
      float sg = 1.f/(1.f+__expf(-c2));
      float v = fmaf(c1,sg,c3); v = v>0.f ? v : 0.f;
      sA += v; qA += v*v; pA.s[r]=f2b(v);
      c1 = acc[i][1][r]+b1B; c2 = acc[i][3][r]+b2B; c3 = acc[i][5][r]+b3B;
      sg = 1.f/(1.f+__expf(-c2));
      v = fmaf(c1,sg,c3); v = v>0.f ? v : 0.f;
      sB += v; qB += v*v; pB.s[r]=f2b(v);
    }
    *(uint2*)&Og[node*256 + coA*8 + t0] = pA.v;
    *(uint2*)&Og[node*256 + coB*8 + t0] = pB.v;
  }
  sA += __shfl_xor(sA,16,64); sA += __shfl_xor(sA,32,64);
  qA += __shfl_xor(qA,16,64); qA += __shfl_xor(qA,32,64);
  sB += __shfl_xor(sB,16,64); sB += __shfl_xor(sB,32,64);
  qB += __shfl_xor(qB,16,64); qB += __shfl_xor(qB,32,64);
  if(lane < 16){
    atomicAdd(&redS[coA], sA); atomicAdd(&redQ[coA], qA);
    atomicAdd(&redS[coB], sB); atomicAdd(&redQ[coB], qB);
  }
  __syncthreads();
  #pragma unroll
  for(int i=0;i<2;i++){
    int idx = i*256 + tid;                // 512 uint4
    *(uint4*)(y2 + (size_t)node0*256 + (size_t)idx*8) = *(const uint4*)&Og[idx*8];
  }
  if(tid<32)      atomicAdd(&bn2_sum[tid], redS[tid]);
  else if(tid<64) atomicAdd(&bn2_sq[tid-32], redQ[tid-32]);
}

// ---------------- final ----------------
__global__ __launch_bounds__(256) void k_final(const us16* __restrict__ y2,
    const float* __restrict__ bn2_sum, const float* __restrict__ bn2_sq,
    const float* __restrict__ bn2g, const float* __restrict__ bn2b,
    const us16* __restrict__ resid, float* __restrict__ out)
{
  __shared__ float fa[32], fb[32];
  const int tid = threadIdx.x;
  if(tid<32){
    float m = bn2_sum[tid]*(1.f/160000.f);
    float v = bn2_sq[tid]*(1.f/160000.f) - m*m;
    float a = bn2g[tid]*rsqrtf(v + 1e-5f);
    fa[tid] = a; fb[tid] = bn2b[tid] - m*a;
  }
  __syncthreads();
  size_t base = ((size_t)blockIdx.x*256 + tid)*8;
  int ch = (int)((base>>3)&31);
  float a = fa[ch], b = fb[ch];
  U4 yv, rv;
  yv.v = *(const uint4*)(y2+base);
  rv.v = *(const uint4*)(resid+base);
  float4 o0, o1;
  float vv[8];
  #pragma unroll
  for(int j=0;j<8;j++){
    float v = fmaf(a, b2f(yv.s[j]), b) + b2f(rv.s[j]);
    vv[j] = v>0.f ? v : 0.f;
  }
  o0.x=vv[0]; o0.y=vv[1]; o0.z=vv[2]; o0.w=vv[3];
  o1.x=vv[4]; o1.y=vv[5]; o1.z=vv[6]; o1.w=vv[7];
  *(float4*)(out+base)   = o0;
  *(float4*)(out+base+4) = o1;
}

extern "C" void kernel_launch(void* const* d_in, const int* in_sizes, int n_in,
                              void* d_out, int out_size, void* d_ws, size_t ws_size,
                              hipStream_t stream)
{
  const float* X    = (const float*)d_in[0];
  const int*  src   = (const int*)d_in[1];
  const int*  dst   = (const int*)d_in[2];
  const float* rp_w = (const float*)d_in[3];
  const float* rp_b = (const float*)d_in[4];
  const float* g1w1 = (const float*)d_in[5];
  const float* g1b1 = (const float*)d_in[6];
  const float* g1w2 = (const float*)d_in[7];
  const float* g1b2 = (const float*)d_in[8];
  const float* g1w3 = (const float*)d_in[9];
  const float* g1b3 = (const float*)d_in[10];
  const float* bn0g = (const float*)d_in[11];
  const float* bn0b = (const float*)d_in[12];
  const float* gatw = (const float*)d_in[13];
  const float* attnl= (const float*)d_in[14];
  const float* attnr= (const float*)d_in[15];
  const float* gbias= (const float*)d_in[16];
  const float* bn1g = (const float*)d_in[17];
  const float* bn1b = (const float*)d_in[18];
  const float* g2w1 = (const float*)d_in[19];
  const float* g2b1 = (const float*)d_in[20];
  const float* g2w2 = (const float*)d_in[21];
  const float* g2b2 = (const float*)d_in[22];
  const float* g2w3 = (const float*)d_in[23];
  const float* g2b3 = (const float*)d_in[24];
  const float* bn2g = (const float*)d_in[25];
  const float* bn2b = (const float*)d_in[26];
  float* out = (float*)d_out;
  (void)in_sizes; (void)n_in; (void)out_size; (void)ws_size;

  char* w = (char*)d_ws;
  float* bn0_sum = (float*)w;                 // 32
  float* bn0_sq  = bn0_sum + 32;              // 32
  float* bn1_sum = bn0_sum + 64;              // 1024
  float* bn1_sq  = bn1_sum + 1024;            // 1024
  float* bn2_sum = bn1_sq  + 1024;            // 32
  float* bn2_sq  = bn2_sum + 32;              // 32
  float* wl      = bn2_sq + 32;               // 1024 (zeroed: accumulated atomically)
  float* wr      = wl + 1024;                 // 1024
  int*   counts  = (int*)(wr + 1024);         // 20000
  size_t zeroBytes = (size_t)((char*)(counts + NN) - w);   // ~96.9 KB
  int*   offsets = counts + NN;               // 20004
  int*   cursor  = offsets + 20004;           // 20000
  int*   esrc    = cursor + NN;               // 320000
  float* el      = (float*)(esrc + NE);       // 80000
  float* er      = el + NN*4;                 // 80000
  float* ew      = er + NN*4;                 // 1,280,000
  us16*  wb      = (us16*)(ew + (size_t)NE*4);// 262144
  us16*  resid   = wb + 262144;               // 5,120,000
  us16*  gc1     = resid + 5120000;           // 5,120,000 (raw gated conv1)
  us16*  Axg     = gc1   + 5120000;           // 20,480,000  [hd][node][256]
  us16*  rst     = Axg   + 20480000;          // 20,480,000
  us16*  Wt      = rst   + 20480000;          // 36,864
  us16*  Wt1     = Wt    + 36864;             // 12,288
  us16*  y2      = gc1;                       // alias: gc1 dead after k_agg2

  hipMemsetAsync(d_ws, 0, zeroBytes, stream);
  k_misc<<<1730, 256, 0, stream>>>(gatw, wb, g2w1, g2w2, g2w3, Wt,
                                   g1w1, g1w2, g1w3, rp_w, Wt1,
                                   attnl, attnr, wl, wr, dst, counts);
  k_gemm1<<<1251, 256, 0, stream>>>(X, Wt1, g1b1, g1b2, g1b3, rp_b,
                                    gc1, resid, bn0_sum, bn0_sq,
                                    counts, offsets, cursor);
  k_eler2<<<5000, 256, 0, stream>>>(gc1, bn0_sum, bn0_sq, bn0g, bn0b, wl, wr, el, er);
  k_scatter<<<1250, 256, 0, stream>>>(src, dst, cursor, esrc, el, er, ew);
  k_agg2<<<5000, 256, 0, stream>>>(offsets, esrc, ew, gc1, bn0_sum, bn0_sq, bn0g, bn0b, Axg);
  k_gemm3<<<dim3(157, 4), 512, 0, stream>>>(Axg, wb, gbias, rst, bn1_sum, bn1_sq);
  k_gemm2<<<1250, 256, 0, stream>>>(rst, Wt, bn1_sum, bn1_sq, bn1g, bn1b,
                                    g2b1, g2b2, g2b3, y2, bn2_sum, bn2_sq);
  k_final<<<2500, 256, 0, stream>>>(y2, bn2_sum, bn2_sq, bn2g, bn2b, resid, out);
}